// Round 23
// baseline (82.094 us; speedup 1.0000x reference)
//
#include <hip/hip_runtime.h>
#include <hip/hip_bf16.h>

#define A_TOT 32
#define SEQ 1024
#define DIM 64
#define NT 16          // KV tiles of 64
#define GSTRIDE 1056   // 8-row group stride (1024B data + 32B pad)
#define TILEB (8 * GSTRIDE)

typedef __attribute__((ext_vector_type(8))) short short8;
typedef __attribute__((ext_vector_type(4))) float f32x4;
typedef unsigned long long u64;

static __device__ __forceinline__ unsigned pack2bf(float a, float b) {
    union { __hip_bfloat16 h[2]; unsigned u; } x;
    x.h[0] = __float2bfloat16(a);
    x.h[1] = __float2bfloat16(b);
    return x.u;
}

// async 16B/lane global->LDS (dest = uniform base + lane*16, linear)
static __device__ __forceinline__ void gload_lds16(const void* g, void* l) {
    __builtin_amdgcn_global_load_lds(
        (const __attribute__((address_space(1))) unsigned*)g,
        (__attribute__((address_space(3))) unsigned*)l, 16, 0, 0);
}

// swizzled 16B fragment read: tile-local row, chunk (8 bf16)
static __device__ __forceinline__ short8 lds_frag(const unsigned char* tile,
                                                  int row, int chunk) {
    const int byte = (row >> 3) * GSTRIDE + (row & 7) * 128 +
                     ((chunk ^ (row & 7)) << 4);
    return *reinterpret_cast<const short8*>(tile + byte);
}

// Counted-wait barrier (guide rule #18 fencing). N = exact count of VMEM ops
// newer than the op we must drain (ledger at call sites).
#define WAITBAR(N) do {                                          \
    asm volatile("s_waitcnt vmcnt(" #N ")" ::: "memory");        \
    __builtin_amdgcn_sched_barrier(0);                           \
    __builtin_amdgcn_s_barrier();                                \
    __builtin_amdgcn_sched_barrier(0);                           \
    asm volatile("" ::: "memory");                               \
} while (0)

// ------------- fused prepass: casts + V transpose + adj bitmask (1 launch) ----
__global__ void prepass_kernel(const float* __restrict__ q,
                               const float* __restrict__ k,
                               const float* __restrict__ v,
                               const int* __restrict__ adj,
                               __hip_bfloat16* __restrict__ qb,
                               __hip_bfloat16* __restrict__ kb,
                               __hip_bfloat16* __restrict__ vt,
                               u64* __restrict__ adjm) {
    __shared__ __hip_bfloat16 tile[64][65];
    const int tid = threadIdx.x;
    if (blockIdx.y < 2) {
        const float* src = blockIdx.y ? k : q;
        __hip_bfloat16* dst = blockIdx.y ? kb : qb;
        int i = (blockIdx.x * 256 + tid) * 4;
        float4 f = *reinterpret_cast<const float4*>(src + i);
        union { __hip_bfloat16 h[4]; ushort4 u; } cv;
        cv.h[0] = __float2bfloat16(f.x);
        cv.h[1] = __float2bfloat16(f.y);
        cv.h[2] = __float2bfloat16(f.z);
        cv.h[3] = __float2bfloat16(f.w);
        *reinterpret_cast<ushort4*>(dst + i) = cv.u;
        return;
    }
    if (blockIdx.x < 512) {
        const int bh = blockIdx.x >> 4;
        const int n0 = (blockIdx.x & 15) * 64;
        const float* vsrc = v + ((size_t)bh * SEQ + n0) * DIM;
        for (int e = tid; e < 64 * 64; e += 256) {
            int i = e >> 6;
            int d = e & 63;
            tile[i][d] = __float2bfloat16(vsrc[(size_t)i * DIM + d]);
        }
        __syncthreads();
        __hip_bfloat16* vdst = vt + (size_t)bh * DIM * SEQ + n0;
        for (int e = tid; e < 64 * 64; e += 256) {
            int d = e >> 6;
            int i = e & 63;
            vdst[(size_t)d * SEQ + i] = tile[i][d];
        }
        return;
    }
    if (blockIdx.x < 1536) {
        const int px   = blockIdx.x - 512;
        const int wv   = tid >> 6;
        const int lane = tid & 63;
        const int wbase = px * 64 + wv * 16;
        for (int it = 0; it < 16; ++it) {
            const int w = wbase + it;
            const int a = adj[(size_t)w * 64 + lane];
            u64 m = __ballot(a > 0);
            if (lane == 0) adjm[w] = m;
        }
    }
}

// ---- kernel A: row-sum partials, split-KV, staged, high occupancy ------------
__launch_bounds__(256)
__global__ void lsum_kernel(const __hip_bfloat16* __restrict__ qb,
                            const __hip_bfloat16* __restrict__ kb,
                            const u64* __restrict__ adjm,
                            float* __restrict__ lpart) {   // [4][32][1024]
    __shared__ __align__(16) unsigned char kstage[2][TILEB];
    __shared__ float part[4][4][16];

    const int wg    = (blockIdx.x & 7) * 256 + (blockIdx.x >> 3);
    const int bh    = wg >> 6;
    const int lidx  = wg & 63;
    const int rb    = lidx >> 2;
    const int kq    = lidx & 3;
    const int batch = bh & 3;
    const int tid   = threadIdx.x;
    const int wid   = tid >> 6;
    const int lane  = tid & 63;
    const int lr    = lane & 15;
    const int lgi   = lane >> 4;
    const int row16 = rb * 64 + wid * 16;
    const int t0    = kq * 4;

    const int sub  = lane >> 3;
    const int csrc = (lane & 7) ^ sub;

    const __hip_bfloat16* qrow = qb + ((size_t)bh * SEQ + row16 + lr) * DIM + lgi * 8;
    const short8 qf0 = *reinterpret_cast<const short8*>(qrow);
    const short8 qf1 = *reinterpret_cast<const short8*>(qrow + 32);

    const u64* mrow = adjm + ((size_t)batch * SEQ + row16 + lr) * (SEQ / 64);
    const __hip_bfloat16* kbh = kb + (size_t)bh * SEQ * DIM;
    const int kperm = (lr >> 2) * 8 + (lr & 3);

    auto stageK = [&](int t, int b) {
        const __hip_bfloat16* g0 = kbh + (size_t)(t * 64 + wid * 16) * DIM;
        unsigned char* l0 = &kstage[b][(wid * 2) * GSTRIDE];
        gload_lds16(g0 + (size_t)sub * DIM + csrc * 8, l0);
        gload_lds16(g0 + (size_t)(8 + sub) * DIM + csrc * 8, l0 + GSTRIDE);
    };

    u64 mb = mrow[t0], mn_ = 0;
    stageK(t0, 0);
    WAITBAR(0);

    float lp = 0.f;
    int cur = 0;
#pragma unroll
    for (int i = 0; i < 4; ++i) {
        const int t = t0 + i;
        if (i < 3) {
            mn_ = mrow[t + 1];
            stageK(t + 1, cur ^ 1);
        }
#pragma unroll
        for (int c = 0; c < 4; ++c) {
            const int cb = (c >> 1) * 32 + (c & 1) * 4;
            const int krow = cb + kperm;
            short8 kf0 = lds_frag(kstage[cur], krow, lgi);
            short8 kf1 = lds_frag(kstage[cur], krow, 4 + lgi);
            f32x4 acc = {0.f, 0.f, 0.f, 0.f};
            acc = __builtin_amdgcn_mfma_f32_16x16x32_bf16(kf0, qf0, acc, 0, 0, 0);
            acc = __builtin_amdgcn_mfma_f32_16x16x32_bf16(kf1, qf1, acc, 0, 0, 0);
            const unsigned b4 = (unsigned)(mb >> (cb + lgi * 8)) & 0xFu;
            float p0 = (b4 & 1u) ? __expf(acc[0] * 0.125f) : 0.f;
            float p1 = (b4 & 2u) ? __expf(acc[1] * 0.125f) : 0.f;
            float p2 = (b4 & 4u) ? __expf(acc[2] * 0.125f) : 0.f;
            float p3 = (b4 & 8u) ? __expf(acc[3] * 0.125f) : 0.f;
            lp += (p0 + p1) + (p2 + p3);
        }
        if (i < 3) {
            mb = mn_;
            WAITBAR(0);
        }
        cur ^= 1;
    }

    part[wid][lgi][lr] = lp;
    asm volatile("" ::: "memory");
    if (lane < 16) {
        float s = part[wid][0][lane] + part[wid][1][lane] +
                  part[wid][2][lane] + part[wid][3][lane];
        lpart[((size_t)kq * A_TOT + bh) * SEQ + row16 + lane] = s;
    }
}

// ---- kernel B: attn + PV; K staged in LDS, V read DIRECT from L2 -------------
// 1D grid 512 blocks, XCD-chunked. 4 waves x 16 rows, full KV. Each XCD's V
// working set (4 bh x 256 KB = 1 MB) fits its 4 MB L2 -> V staging was pure
// overhead (guide common-mistake #7): PV reads V as a register batch of 8
// b128 loads (R9/R10-validated pattern). LDS halves to ~17 KB; half the
// gload_lds + LDS-write port pressure per phase.
__launch_bounds__(256)
__global__ void graph_attn_kernel(const __hip_bfloat16* __restrict__ qb,
                                  const __hip_bfloat16* __restrict__ kb,
                                  const __hip_bfloat16* __restrict__ vt,
                                  const u64* __restrict__ adjm,
                                  const float* __restrict__ lpart,
                                  float* __restrict__ out,    // [32,1024,64]
                                  float* __restrict__ attn) { // [32,1024,1024]
    __shared__ __align__(16) unsigned char kstage[2][TILEB];

    const int wg    = (blockIdx.x & 7) * 64 + (blockIdx.x >> 3);
    const int bh    = wg >> 4;
    const int rb    = wg & 15;
    const int batch = bh & 3;
    const int tid   = threadIdx.x;
    const int wid   = tid >> 6;
    const int lane  = tid & 63;
    const int lr    = lane & 15;
    const int lgi   = lane >> 4;
    const int row16 = rb * 64 + wid * 16;

    const int sub  = lane >> 3;
    const int csrc = (lane & 7) ^ sub;

    const __hip_bfloat16* qrow = qb + ((size_t)bh * SEQ + row16 + lr) * DIM + lgi * 8;
    const short8 qf0 = *reinterpret_cast<const short8*>(qrow);
    const short8 qf1 = *reinterpret_cast<const short8*>(qrow + 32);

    const u64* mrow = adjm + ((size_t)batch * SEQ + row16 + lr) * (SEQ / 64);
    const __hip_bfloat16* kbh = kb + (size_t)bh * SEQ * DIM;
    const __hip_bfloat16* vth = vt + (size_t)bh * DIM * SEQ;

    const int kperm = (lr >> 2) * 8 + (lr & 3);

    auto stageK = [&](int t, int b) {
        const __hip_bfloat16* g0 = kbh + (size_t)(t * 64 + wid * 16) * DIM;
        unsigned char* l0 = &kstage[b][(wid * 2) * GSTRIDE];
        gload_lds16(g0 + (size_t)sub * DIM + csrc * 8, l0);
        gload_lds16(g0 + (size_t)(8 + sub) * DIM + csrc * 8, l0 + GSTRIDE);
    };

    // linv partials (fixed-order sum, deterministic)
    const float* lpr = lpart + (size_t)bh * SEQ + row16 + lr;
    const float a0 = lpr[0];
    const float a1 = lpr[(size_t)A_TOT * SEQ];
    const float a2 = lpr[(size_t)2 * A_TOT * SEQ];
    const float a3 = lpr[(size_t)3 * A_TOT * SEQ];

    u64 mb = mrow[0], mn_ = 0;
    stageK(0, 0);
    WAITBAR(0);  // drains lpart loads + mrow[0] + stage(0)

    const float linv = 1.0f / (((a0 + a1) + (a2 + a3)) + 1e-37f);

    f32x4 o[4];
#pragma unroll
    for (int c = 0; c < 4; ++c) o[c] = (f32x4){0.f, 0.f, 0.f, 0.f};

    float* attn_row = attn + (size_t)bh * SEQ * SEQ + (size_t)(row16 + lr) * SEQ;
    int cur = 0;
    for (int t = 0; t < NT; ++t) {
        const int n0 = t * 64;
        // VMEM issue: mrow(t+1)[1], stageK(t+1)[2]
        if (t < NT - 1) {
            mn_ = mrow[t + 1];
            stageK(t + 1, cur ^ 1);
        }
        __builtin_amdgcn_sched_barrier(0);  // pin: stage issued first
        // V register batch: 8 x b128 direct from L2-resident vt
        short8 vf[4][2];
#pragma unroll
        for (int c2 = 0; c2 < 4; ++c2) {
            const __hip_bfloat16* vrow =
                vth + (size_t)(c2 * 16 + lr) * SEQ + n0 + lgi * 8;
            vf[c2][0] = *reinterpret_cast<const short8*>(vrow);
            vf[c2][1] = *reinterpret_cast<const short8*>(vrow + 32);
        }
        __builtin_amdgcn_sched_barrier(0);  // pin: V issued before QK
        // QK from LDS + normalized p + fp32 attn stores
        unsigned pk[4][2];
#pragma unroll
        for (int c = 0; c < 4; ++c) {
            const int cb = (c >> 1) * 32 + (c & 1) * 4;
            const int krow = cb + kperm;
            short8 kf0 = lds_frag(kstage[cur], krow, lgi);
            short8 kf1 = lds_frag(kstage[cur], krow, 4 + lgi);
            f32x4 acc = {0.f, 0.f, 0.f, 0.f};
            acc = __builtin_amdgcn_mfma_f32_16x16x32_bf16(kf0, qf0, acc, 0, 0, 0);
            acc = __builtin_amdgcn_mfma_f32_16x16x32_bf16(kf1, qf1, acc, 0, 0, 0);
            const unsigned b4 = (unsigned)(mb >> (cb + lgi * 8)) & 0xFu;
            float p0 = (b4 & 1u) ? __expf(acc[0] * 0.125f) * linv : 0.f;
            float p1 = (b4 & 2u) ? __expf(acc[1] * 0.125f) * linv : 0.f;
            float p2 = (b4 & 4u) ? __expf(acc[2] * 0.125f) * linv : 0.f;
            float p3 = (b4 & 8u) ? __expf(acc[3] * 0.125f) * linv : 0.f;
            *reinterpret_cast<float4*>(attn_row + n0 + cb + lgi * 8) =
                (float4){p0, p1, p2, p3};
            pk[c][0] = pack2bf(p0, p1);
            pk[c][1] = pack2bf(p2, p3);
        }
        // PV (compiler inserts counted vmcnt for vf; stageK is older -> also
        // drained here, giving tile t+1 one-QK-phase of cover)
        union { unsigned u[4]; short8 s; } pf0, pf1;
        pf0.u[0] = pk[0][0]; pf0.u[1] = pk[0][1];
        pf0.u[2] = pk[1][0]; pf0.u[3] = pk[1][1];
        pf1.u[0] = pk[2][0]; pf1.u[1] = pk[2][1];
        pf1.u[2] = pk[3][0]; pf1.u[3] = pk[3][1];
#pragma unroll
        for (int c2 = 0; c2 < 4; ++c2) {
            o[c2] = __builtin_amdgcn_mfma_f32_16x16x32_bf16(pf0.s, vf[c2][0], o[c2], 0, 0, 0);
            o[c2] = __builtin_amdgcn_mfma_f32_16x16x32_bf16(pf1.s, vf[c2][1], o[c2], 0, 0, 0);
        }
        if (t < NT - 1) {
            mb = mn_;
            // ledger: stores(t)[4] are the only ops newer than stageK(t+1);
            // PV's implicit V-wait already drained stageK, so this is just
            // the cross-wave publication barrier. Leave stores in flight.
            WAITBAR(4);
        }
        cur ^= 1;
    }

    // ---- O epilogue: already normalized ----
    float* ob = out + (size_t)bh * SEQ * DIM + (size_t)row16 * DIM;
#pragma unroll
    for (int c2 = 0; c2 < 4; ++c2)
#pragma unroll
        for (int j = 0; j < 4; ++j)
            ob[(size_t)(lgi * 4 + j) * DIM + c2 * 16 + lr] = o[c2][j];
}

extern "C" void kernel_launch(void* const* d_in, const int* in_sizes, int n_in,
                              void* d_out, int out_size, void* d_ws, size_t ws_size,
                              hipStream_t stream) {
    const float* q   = (const float*)d_in[0];
    const float* k   = (const float*)d_in[1];
    const float* v   = (const float*)d_in[2];
    const int*   adj = (const int*)d_in[3];

    float* out  = (float*)d_out;                   // [32,1024,64]
    float* attn = out + (size_t)A_TOT * SEQ * DIM; // [32,1024,1024]

    __hip_bfloat16* qb = (__hip_bfloat16*)d_ws;
    __hip_bfloat16* kb = qb + (size_t)A_TOT * SEQ * DIM;
    __hip_bfloat16* vt = kb + (size_t)A_TOT * SEQ * DIM;
    u64* adjm = (u64*)(vt + (size_t)A_TOT * SEQ * DIM);        // 512 KB
    float* lpart = (float*)(adjm + 4 * SEQ * (SEQ / 64));      // 512 KB

    prepass_kernel<<<dim3(2048, 3), 256, 0, stream>>>(q, k, v, adj, qb, kb, vt, adjm);
    lsum_kernel<<<2048, 256, 0, stream>>>(qb, kb, adjm, lpart);
    graph_attn_kernel<<<512, 256, 0, stream>>>(qb, kb, vt, adjm, lpart, out, attn);
}

// Round 24
// 65.661 us; speedup vs baseline: 1.2503x; 1.2503x over previous
//
#include <hip/hip_runtime.h>
#include <hip/hip_bf16.h>

#define A_TOT 32
#define SEQ 1024
#define DIM 64
#define NT 16          // KV tiles of 64
#define GSTRIDE 1056   // 8-row group stride (1024B data + 32B pad)
#define TILEB (8 * GSTRIDE)

typedef __attribute__((ext_vector_type(8))) short short8;
typedef __attribute__((ext_vector_type(4))) float f32x4;
typedef unsigned long long u64;

static __device__ __forceinline__ unsigned pack2bf(float a, float b) {
    union { __hip_bfloat16 h[2]; unsigned u; } x;
    x.h[0] = __float2bfloat16(a);
    x.h[1] = __float2bfloat16(b);
    return x.u;
}

// async 16B/lane global->LDS (dest = uniform base + lane*16, linear)
static __device__ __forceinline__ void gload_lds16(const void* g, void* l) {
    __builtin_amdgcn_global_load_lds(
        (const __attribute__((address_space(1))) unsigned*)g,
        (__attribute__((address_space(3))) unsigned*)l, 16, 0, 0);
}

// swizzled 16B fragment read: tile-local row, chunk (8 bf16)
static __device__ __forceinline__ short8 lds_frag(const unsigned char* tile,
                                                  int row, int chunk) {
    const int byte = (row >> 3) * GSTRIDE + (row & 7) * 128 +
                     ((chunk ^ (row & 7)) << 4);
    return *reinterpret_cast<const short8*>(tile + byte);
}

// Counted-wait barrier (guide rule #18 fencing). N = exact count of VMEM ops
// newer than the op we must drain (ledger at call sites).
#define WAITBAR(N) do {                                          \
    asm volatile("s_waitcnt vmcnt(" #N ")" ::: "memory");        \
    __builtin_amdgcn_sched_barrier(0);                           \
    __builtin_amdgcn_s_barrier();                                \
    __builtin_amdgcn_sched_barrier(0);                           \
    asm volatile("" ::: "memory");                               \
} while (0)

// ------------- fused prepass: casts + V transpose + adj bitmask (1 launch) ----
__global__ void prepass_kernel(const float* __restrict__ q,
                               const float* __restrict__ k,
                               const float* __restrict__ v,
                               const int* __restrict__ adj,
                               __hip_bfloat16* __restrict__ qb,
                               __hip_bfloat16* __restrict__ kb,
                               __hip_bfloat16* __restrict__ vt,
                               u64* __restrict__ adjm) {
    __shared__ __hip_bfloat16 tile[64][65];
    const int tid = threadIdx.x;
    if (blockIdx.y < 2) {
        const float* src = blockIdx.y ? k : q;
        __hip_bfloat16* dst = blockIdx.y ? kb : qb;
        int i = (blockIdx.x * 256 + tid) * 4;
        float4 f = *reinterpret_cast<const float4*>(src + i);
        union { __hip_bfloat16 h[4]; ushort4 u; } cv;
        cv.h[0] = __float2bfloat16(f.x);
        cv.h[1] = __float2bfloat16(f.y);
        cv.h[2] = __float2bfloat16(f.z);
        cv.h[3] = __float2bfloat16(f.w);
        *reinterpret_cast<ushort4*>(dst + i) = cv.u;
        return;
    }
    if (blockIdx.x < 512) {
        const int bh = blockIdx.x >> 4;
        const int n0 = (blockIdx.x & 15) * 64;
        const float* vsrc = v + ((size_t)bh * SEQ + n0) * DIM;
        for (int e = tid; e < 64 * 64; e += 256) {
            int i = e >> 6;
            int d = e & 63;
            tile[i][d] = __float2bfloat16(vsrc[(size_t)i * DIM + d]);
        }
        __syncthreads();
        __hip_bfloat16* vdst = vt + (size_t)bh * DIM * SEQ + n0;
        for (int e = tid; e < 64 * 64; e += 256) {
            int d = e >> 6;
            int i = e & 63;
            vdst[(size_t)d * SEQ + i] = tile[i][d];
        }
        return;
    }
    if (blockIdx.x < 1536) {
        const int px   = blockIdx.x - 512;
        const int wv   = tid >> 6;
        const int lane = tid & 63;
        const int wbase = px * 64 + wv * 16;
        for (int it = 0; it < 16; ++it) {
            const int w = wbase + it;
            const int a = adj[(size_t)w * 64 + lane];
            u64 m = __ballot(a > 0);
            if (lane == 0) adjm[w] = m;
        }
    }
}

// ---- kernel A: row-sum partials, split-KV, staged, high occupancy ------------
__launch_bounds__(256)
__global__ void lsum_kernel(const __hip_bfloat16* __restrict__ qb,
                            const __hip_bfloat16* __restrict__ kb,
                            const u64* __restrict__ adjm,
                            float* __restrict__ lpart) {   // [4][32][1024]
    __shared__ __align__(16) unsigned char kstage[2][TILEB];
    __shared__ float part[4][4][16];

    const int wg    = (blockIdx.x & 7) * 256 + (blockIdx.x >> 3);
    const int bh    = wg >> 6;
    const int lidx  = wg & 63;
    const int rb    = lidx >> 2;
    const int kq    = lidx & 3;
    const int batch = bh & 3;
    const int tid   = threadIdx.x;
    const int wid   = tid >> 6;
    const int lane  = tid & 63;
    const int lr    = lane & 15;
    const int lgi   = lane >> 4;
    const int row16 = rb * 64 + wid * 16;
    const int t0    = kq * 4;

    const int sub  = lane >> 3;
    const int csrc = (lane & 7) ^ sub;

    const __hip_bfloat16* qrow = qb + ((size_t)bh * SEQ + row16 + lr) * DIM + lgi * 8;
    const short8 qf0 = *reinterpret_cast<const short8*>(qrow);
    const short8 qf1 = *reinterpret_cast<const short8*>(qrow + 32);

    const u64* mrow = adjm + ((size_t)batch * SEQ + row16 + lr) * (SEQ / 64);
    const __hip_bfloat16* kbh = kb + (size_t)bh * SEQ * DIM;
    const int kperm = (lr >> 2) * 8 + (lr & 3);

    auto stageK = [&](int t, int b) {
        const __hip_bfloat16* g0 = kbh + (size_t)(t * 64 + wid * 16) * DIM;
        unsigned char* l0 = &kstage[b][(wid * 2) * GSTRIDE];
        gload_lds16(g0 + (size_t)sub * DIM + csrc * 8, l0);
        gload_lds16(g0 + (size_t)(8 + sub) * DIM + csrc * 8, l0 + GSTRIDE);
    };

    u64 mb = mrow[t0], mn_ = 0;
    stageK(t0, 0);
    WAITBAR(0);

    float lp = 0.f;
    int cur = 0;
#pragma unroll
    for (int i = 0; i < 4; ++i) {
        const int t = t0 + i;
        if (i < 3) {
            mn_ = mrow[t + 1];
            stageK(t + 1, cur ^ 1);
        }
#pragma unroll
        for (int c = 0; c < 4; ++c) {
            const int cb = (c >> 1) * 32 + (c & 1) * 4;
            const int krow = cb + kperm;
            short8 kf0 = lds_frag(kstage[cur], krow, lgi);
            short8 kf1 = lds_frag(kstage[cur], krow, 4 + lgi);
            f32x4 acc = {0.f, 0.f, 0.f, 0.f};
            acc = __builtin_amdgcn_mfma_f32_16x16x32_bf16(kf0, qf0, acc, 0, 0, 0);
            acc = __builtin_amdgcn_mfma_f32_16x16x32_bf16(kf1, qf1, acc, 0, 0, 0);
            const unsigned b4 = (unsigned)(mb >> (cb + lgi * 8)) & 0xFu;
            float p0 = (b4 & 1u) ? __expf(acc[0] * 0.125f) : 0.f;
            float p1 = (b4 & 2u) ? __expf(acc[1] * 0.125f) : 0.f;
            float p2 = (b4 & 4u) ? __expf(acc[2] * 0.125f) : 0.f;
            float p3 = (b4 & 8u) ? __expf(acc[3] * 0.125f) : 0.f;
            lp += (p0 + p1) + (p2 + p3);
        }
        if (i < 3) {
            mb = mn_;
            WAITBAR(0);
        }
        cur ^= 1;
    }

    part[wid][lgi][lr] = lp;
    asm volatile("" ::: "memory");
    if (lane < 16) {
        float s = part[wid][0][lane] + part[wid][1][lane] +
                  part[wid][2][lane] + part[wid][3][lane];
        lpart[((size_t)kq * A_TOT + bh) * SEQ + row16 + lane] = s;
    }
}

// ---- kernel B: attn + PV, 2-wave blocks -> 4 barrier domains per CU ----------
// grid 1024 x 128 threads (XCD-chunked). Block = 32 rows x full KV; per CU
// FOUR blocks co-reside (LDS 33.8 KB each) -> 4 independent barrier domains
// (vs 2): while one block drains its barrier, three others compute. K+V
// double-buffer staged (each wave stages half the 64-row tile = 4 gload_lds
// per array). Exact per-wave vmcnt ledger as validated in R20/R22.
__launch_bounds__(128)
__global__ void graph_attn_kernel(const __hip_bfloat16* __restrict__ qb,
                                  const __hip_bfloat16* __restrict__ kb,
                                  const __hip_bfloat16* __restrict__ vt,
                                  const u64* __restrict__ adjm,
                                  const float* __restrict__ lpart,
                                  float* __restrict__ out,    // [32,1024,64]
                                  float* __restrict__ attn) { // [32,1024,1024]
    __shared__ __align__(16) unsigned char kstage[2][TILEB];
    __shared__ __align__(16) unsigned char vstage[2][TILEB];

    // XCD-chunked bijective swizzle: 1024 blocks, 8 XCDs, 128 per XCD
    const int wg    = (blockIdx.x & 7) * 128 + (blockIdx.x >> 3);
    const int bh    = wg >> 5;         // 4 bh per XCD
    const int rb    = wg & 31;         // 32 row-blocks of 32 rows
    const int batch = bh & 3;
    const int tid   = threadIdx.x;
    const int wid   = tid >> 6;        // 0..1
    const int lane  = tid & 63;
    const int lr    = lane & 15;
    const int lgi   = lane >> 4;
    const int row16 = rb * 32 + wid * 16;

    const int sub  = lane >> 3;
    const int csrc = (lane & 7) ^ sub;

    const __hip_bfloat16* qrow = qb + ((size_t)bh * SEQ + row16 + lr) * DIM + lgi * 8;
    const short8 qf0 = *reinterpret_cast<const short8*>(qrow);
    const short8 qf1 = *reinterpret_cast<const short8*>(qrow + 32);

    const u64* mrow = adjm + ((size_t)batch * SEQ + row16 + lr) * (SEQ / 64);
    const __hip_bfloat16* kbh = kb + (size_t)bh * SEQ * DIM;
    const __hip_bfloat16* vth = vt + (size_t)bh * DIM * SEQ;

    const int kperm = (lr >> 2) * 8 + (lr & 3);

    // each wave stages HALF the 64-row tile: 4 x 8-row groups
    auto stageK = [&](int t, int b) {
        const __hip_bfloat16* g0 = kbh + (size_t)(t * 64 + wid * 32) * DIM;
        unsigned char* l0 = &kstage[b][(wid * 4) * GSTRIDE];
#pragma unroll
        for (int g = 0; g < 4; ++g)
            gload_lds16(g0 + (size_t)(g * 8 + sub) * DIM + csrc * 8,
                        l0 + g * GSTRIDE);
    };
    auto stageV = [&](int t, int b) {
        const __hip_bfloat16* g0 = vth + (size_t)(wid * 32) * SEQ + t * 64;
        unsigned char* l0 = &vstage[b][(wid * 4) * GSTRIDE];
#pragma unroll
        for (int g = 0; g < 4; ++g)
            gload_lds16(g0 + (size_t)(g * 8 + sub) * SEQ + csrc * 8,
                        l0 + g * GSTRIDE);
    };

    // linv partials (fixed-order sum, deterministic)
    const float* lpr = lpart + (size_t)bh * SEQ + row16 + lr;
    const float a0 = lpr[0];
    const float a1 = lpr[(size_t)A_TOT * SEQ];
    const float a2 = lpr[(size_t)2 * A_TOT * SEQ];
    const float a3 = lpr[(size_t)3 * A_TOT * SEQ];

    u64 mb = mrow[0], mn_ = 0;
    stageK(0, 0); stageV(0, 0);
    WAITBAR(0);  // drains lpart/mrow loads + stage(0)

    const float linv = 1.0f / (((a0 + a1) + (a2 + a3)) + 1e-37f);

    f32x4 o[4];
#pragma unroll
    for (int c = 0; c < 4; ++c) o[c] = (f32x4){0.f, 0.f, 0.f, 0.f};

    float* attn_row = attn + (size_t)bh * SEQ * SEQ + (size_t)(row16 + lr) * SEQ;
    int cur = 0;
    for (int t = 0; t < NT; ++t) {
        const int n0 = t * 64;
        // VMEM issue: mrow(t+1)[1], stage(t+1)[8], then stores(t)[4] in c-loop
        if (t < NT - 1) {
            mn_ = mrow[t + 1];
            stageK(t + 1, cur ^ 1);
            stageV(t + 1, cur ^ 1);
        }
        __builtin_amdgcn_sched_barrier(0);  // pin: stage issued before stores
        unsigned pk[4][2];
#pragma unroll
        for (int c = 0; c < 4; ++c) {
            const int cb = (c >> 1) * 32 + (c & 1) * 4;
            const int krow = cb + kperm;
            short8 kf0 = lds_frag(kstage[cur], krow, lgi);
            short8 kf1 = lds_frag(kstage[cur], krow, 4 + lgi);
            f32x4 acc = {0.f, 0.f, 0.f, 0.f};
            acc = __builtin_amdgcn_mfma_f32_16x16x32_bf16(kf0, qf0, acc, 0, 0, 0);
            acc = __builtin_amdgcn_mfma_f32_16x16x32_bf16(kf1, qf1, acc, 0, 0, 0);
            const unsigned b4 = (unsigned)(mb >> (cb + lgi * 8)) & 0xFu;
            float p0 = (b4 & 1u) ? __expf(acc[0] * 0.125f) * linv : 0.f;
            float p1 = (b4 & 2u) ? __expf(acc[1] * 0.125f) * linv : 0.f;
            float p2 = (b4 & 4u) ? __expf(acc[2] * 0.125f) * linv : 0.f;
            float p3 = (b4 & 8u) ? __expf(acc[3] * 0.125f) * linv : 0.f;
            *reinterpret_cast<float4*>(attn_row + n0 + cb + lgi * 8) =
                (float4){p0, p1, p2, p3};
            pk[c][0] = pack2bf(p0, p1);
            pk[c][1] = pack2bf(p2, p3);
        }
        // PV on normalized p (register-concat fragments, validated mapping)
        union { unsigned u[4]; short8 s; } pf0, pf1;
        pf0.u[0] = pk[0][0]; pf0.u[1] = pk[0][1];
        pf0.u[2] = pk[1][0]; pf0.u[3] = pk[1][1];
        pf1.u[0] = pk[2][0]; pf1.u[1] = pk[2][1];
        pf1.u[2] = pk[3][0]; pf1.u[3] = pk[3][1];
#pragma unroll
        for (int c2 = 0; c2 < 4; ++c2) {
            const int vrow = c2 * 16 + lr;
            short8 vf0 = lds_frag(vstage[cur], vrow, lgi);
            short8 vf1 = lds_frag(vstage[cur], vrow, 4 + lgi);
            o[c2] = __builtin_amdgcn_mfma_f32_16x16x32_bf16(pf0.s, vf0, o[c2], 0, 0, 0);
            o[c2] = __builtin_amdgcn_mfma_f32_16x16x32_bf16(pf1.s, vf1, o[c2], 0, 0, 0);
        }
        if (t < NT - 1) {
            mb = mn_;
            // ledger (oldest->newest): [stores(t-1) leftovers <=4], mrow(t+1)[1],
            // stage(t+1)[8], stores(t)[4] -> drain stage(t+1), leave stores(t).
            WAITBAR(4);
        }
        cur ^= 1;
    }

    // ---- O epilogue: already normalized ----
    float* ob = out + (size_t)bh * SEQ * DIM + (size_t)row16 * DIM;
#pragma unroll
    for (int c2 = 0; c2 < 4; ++c2)
#pragma unroll
        for (int j = 0; j < 4; ++j)
            ob[(size_t)(lgi * 4 + j) * DIM + c2 * 16 + lr] = o[c2][j];
}

extern "C" void kernel_launch(void* const* d_in, const int* in_sizes, int n_in,
                              void* d_out, int out_size, void* d_ws, size_t ws_size,
                              hipStream_t stream) {
    const float* q   = (const float*)d_in[0];
    const float* k   = (const float*)d_in[1];
    const float* v   = (const float*)d_in[2];
    const int*   adj = (const int*)d_in[3];

    float* out  = (float*)d_out;                   // [32,1024,64]
    float* attn = out + (size_t)A_TOT * SEQ * DIM; // [32,1024,1024]

    __hip_bfloat16* qb = (__hip_bfloat16*)d_ws;
    __hip_bfloat16* kb = qb + (size_t)A_TOT * SEQ * DIM;
    __hip_bfloat16* vt = kb + (size_t)A_TOT * SEQ * DIM;
    u64* adjm = (u64*)(vt + (size_t)A_TOT * SEQ * DIM);        // 512 KB
    float* lpart = (float*)(adjm + 4 * SEQ * (SEQ / 64));      // 512 KB

    prepass_kernel<<<dim3(2048, 3), 256, 0, stream>>>(q, k, v, adj, qb, kb, vt, adjm);
    lsum_kernel<<<2048, 256, 0, stream>>>(qb, kb, adjm, lpart);
    graph_attn_kernel<<<1024, 128, 0, stream>>>(qb, kb, vt, adjm, lpart, out, attn);
}

// Round 25
// 61.751 us; speedup vs baseline: 1.3294x; 1.0633x over previous
//
#include <hip/hip_runtime.h>
#include <hip/hip_bf16.h>

#define A_TOT 32
#define SEQ 1024
#define DIM 64
#define NT 16          // KV tiles of 64
#define GSTRIDE 1056   // 8-row group stride (1024B data + 32B pad)
#define TILEB (8 * GSTRIDE)

typedef __attribute__((ext_vector_type(8))) short short8;
typedef __attribute__((ext_vector_type(4))) float f32x4;
typedef unsigned long long u64;

static __device__ __forceinline__ unsigned pack2bf(float a, float b) {
    union { __hip_bfloat16 h[2]; unsigned u; } x;
    x.h[0] = __float2bfloat16(a);
    x.h[1] = __float2bfloat16(b);
    return x.u;
}

// async 16B/lane global->LDS (dest = uniform base + lane*16, linear)
static __device__ __forceinline__ void gload_lds16(const void* g, void* l) {
    __builtin_amdgcn_global_load_lds(
        (const __attribute__((address_space(1))) unsigned*)g,
        (__attribute__((address_space(3))) unsigned*)l, 16, 0, 0);
}

// swizzled 16B fragment read: tile-local row, chunk (8 bf16)
static __device__ __forceinline__ short8 lds_frag(const unsigned char* tile,
                                                  int row, int chunk) {
    const int byte = (row >> 3) * GSTRIDE + (row & 7) * 128 +
                     ((chunk ^ (row & 7)) << 4);
    return *reinterpret_cast<const short8*>(tile + byte);
}

// Counted-wait barrier (guide rule #18 fencing). N = exact count of VMEM ops
// newer than the op we must drain (ledger at call sites).
#define WAITBAR(N) do {                                          \
    asm volatile("s_waitcnt vmcnt(" #N ")" ::: "memory");        \
    __builtin_amdgcn_sched_barrier(0);                           \
    __builtin_amdgcn_s_barrier();                                \
    __builtin_amdgcn_sched_barrier(0);                           \
    asm volatile("" ::: "memory");                               \
} while (0)

// ------------- fused prepass: casts + V transpose + adj bitmask (1 launch) ----
__global__ void prepass_kernel(const float* __restrict__ q,
                               const float* __restrict__ k,
                               const float* __restrict__ v,
                               const int* __restrict__ adj,
                               __hip_bfloat16* __restrict__ qb,
                               __hip_bfloat16* __restrict__ kb,
                               __hip_bfloat16* __restrict__ vt,
                               u64* __restrict__ adjm) {
    __shared__ __hip_bfloat16 tile[64][65];
    const int tid = threadIdx.x;
    if (blockIdx.y < 2) {
        const float* src = blockIdx.y ? k : q;
        __hip_bfloat16* dst = blockIdx.y ? kb : qb;
        int i = (blockIdx.x * 256 + tid) * 4;
        float4 f = *reinterpret_cast<const float4*>(src + i);
        union { __hip_bfloat16 h[4]; ushort4 u; } cv;
        cv.h[0] = __float2bfloat16(f.x);
        cv.h[1] = __float2bfloat16(f.y);
        cv.h[2] = __float2bfloat16(f.z);
        cv.h[3] = __float2bfloat16(f.w);
        *reinterpret_cast<ushort4*>(dst + i) = cv.u;
        return;
    }
    if (blockIdx.x < 512) {
        // V transpose+cast: [bh][n][d] -> [bh][d][n]
        const int bh = blockIdx.x >> 4;
        const int n0 = (blockIdx.x & 15) * 64;
        const float* vsrc = v + ((size_t)bh * SEQ + n0) * DIM;
        for (int e = tid; e < 64 * 64; e += 256) {
            int i = e >> 6;
            int d = e & 63;
            tile[i][d] = __float2bfloat16(vsrc[(size_t)i * DIM + d]);
        }
        __syncthreads();
        __hip_bfloat16* vdst = vt + (size_t)bh * DIM * SEQ + n0;
        for (int e = tid; e < 64 * 64; e += 256) {
            int d = e >> 6;
            int i = e & 63;
            vdst[(size_t)d * SEQ + i] = tile[i][d];
        }
        return;
    }
    if (blockIdx.x < 1536) {
        // adj -> 1024-bit row masks; word w covers cols [w*64,+64)
        const int px   = blockIdx.x - 512;
        const int wv   = tid >> 6;
        const int lane = tid & 63;
        const int wbase = px * 64 + wv * 16;
        for (int it = 0; it < 16; ++it) {
            const int w = wbase + it;
            const int a = adj[(size_t)w * 64 + lane];
            u64 m = __ballot(a > 0);
            if (lane == 0) adjm[w] = m;
        }
    }
}

// ------- fused masked attention: double-buffered, counted-vmcnt pipeline ------
// 1D grid 512 blocks, XCD-chunked swizzle. 4 waves x 16 rows.
// Sweep A: row sums l (K staged).  Sweep B: normalized attn + PV (K+V staged).
// Best measured configuration (R20, 61.98 us).
__launch_bounds__(256)
__global__ void graph_attn_kernel(const __hip_bfloat16* __restrict__ qb,
                                  const __hip_bfloat16* __restrict__ kb,
                                  const __hip_bfloat16* __restrict__ vt,
                                  const u64* __restrict__ adjm,
                                  float* __restrict__ out,    // [32,1024,64]
                                  float* __restrict__ attn) { // [32,1024,1024]
    __shared__ __align__(16) unsigned char kstage[2][TILEB];
    __shared__ __align__(16) unsigned char vstage[2][TILEB];
    __shared__ float part[4][4][16];
    __shared__ float lsum_sh[4][16];

    // XCD-chunked bijective swizzle: 512 blocks, 8 XCDs, 64 per XCD
    const int wg    = (blockIdx.x & 7) * 64 + (blockIdx.x >> 3);
    const int bh    = wg >> 4;
    const int rb    = wg & 15;
    const int batch = bh & 3;
    const int tid   = threadIdx.x;
    const int wid   = tid >> 6;
    const int lane  = tid & 63;
    const int lr    = lane & 15;
    const int lgi   = lane >> 4;
    const int row16 = rb * 64 + wid * 16;

    const int sub  = lane >> 3;          // staging: row within 8-row group
    const int csrc = (lane & 7) ^ sub;   // pre-swizzled source chunk

    const __hip_bfloat16* qrow = qb + ((size_t)bh * SEQ + row16 + lr) * DIM + lgi * 8;
    const short8 qf0 = *reinterpret_cast<const short8*>(qrow);
    const short8 qf1 = *reinterpret_cast<const short8*>(qrow + 32);

    const u64* mrow = adjm + ((size_t)batch * SEQ + row16 + lr) * (SEQ / 64);
    const __hip_bfloat16* kbh = kb + (size_t)bh * SEQ * DIM;
    const __hip_bfloat16* vth = vt + (size_t)bh * DIM * SEQ;

    const int kperm = (lr >> 2) * 8 + (lr & 3);  // validated R7 row permutation

    auto stageK = [&](int t, int b) {
        const __hip_bfloat16* g0 = kbh + (size_t)(t * 64 + wid * 16) * DIM;
        unsigned char* l0 = &kstage[b][(wid * 2) * GSTRIDE];
        gload_lds16(g0 + (size_t)sub * DIM + csrc * 8, l0);
        gload_lds16(g0 + (size_t)(8 + sub) * DIM + csrc * 8, l0 + GSTRIDE);
    };
    auto stageV = [&](int t, int b) {
        const __hip_bfloat16* g0 = vth + (size_t)(wid * 16) * SEQ + t * 64;
        unsigned char* l0 = &vstage[b][(wid * 2) * GSTRIDE];
        gload_lds16(g0 + (size_t)sub * SEQ + csrc * 8, l0);
        gload_lds16(g0 + (size_t)(8 + sub) * SEQ + csrc * 8, l0 + GSTRIDE);
    };

    // ================= sweep A: row sums =================
    u64 mb = mrow[0], mn_ = 0;
    stageK(0, 0);
    WAITBAR(0);  // drain mrow[0] + stage(0)

    float lp = 0.f;
    int cur = 0;
    for (int t = 0; t < NT; ++t) {
        if (t < NT - 1) {
            mn_ = mrow[t + 1];
            stageK(t + 1, cur ^ 1);
        }
#pragma unroll
        for (int c = 0; c < 4; ++c) {
            const int cb = (c >> 1) * 32 + (c & 1) * 4;
            const int krow = cb + kperm;
            short8 kf0 = lds_frag(kstage[cur], krow, lgi);
            short8 kf1 = lds_frag(kstage[cur], krow, 4 + lgi);
            f32x4 acc = {0.f, 0.f, 0.f, 0.f};
            acc = __builtin_amdgcn_mfma_f32_16x16x32_bf16(kf0, qf0, acc, 0, 0, 0);
            acc = __builtin_amdgcn_mfma_f32_16x16x32_bf16(kf1, qf1, acc, 0, 0, 0);
            const unsigned b4 = (unsigned)(mb >> (cb + lgi * 8)) & 0xFu;
            float p0 = (b4 & 1u) ? __expf(acc[0] * 0.125f) : 0.f;
            float p1 = (b4 & 2u) ? __expf(acc[1] * 0.125f) : 0.f;
            float p2 = (b4 & 4u) ? __expf(acc[2] * 0.125f) : 0.f;
            float p3 = (b4 & 8u) ? __expf(acc[3] * 0.125f) : 0.f;
            lp += (p0 + p1) + (p2 + p3);
        }
        if (t < NT - 1) {
            mb = mn_;
            WAITBAR(0);  // ledger: mrow[1], stageK(t+1)[2]; drain all
        }
        cur ^= 1;
    }

    // wave-local row sums (same-wave LDS, validated pattern)
    part[wid][lgi][lr] = lp;
    asm volatile("" ::: "memory");
    if (lane < 16) {
        lsum_sh[wid][lane] = part[wid][0][lane] + part[wid][1][lane] +
                             part[wid][2][lane] + part[wid][3][lane];
    }
    __syncthreads();  // also guards kstage reuse below
    const float linv = 1.0f / (lsum_sh[wid][lr] + 1e-37f);

    // ================= sweep B: attn + PV =================
    f32x4 o[4];
#pragma unroll
    for (int c = 0; c < 4; ++c) o[c] = (f32x4){0.f, 0.f, 0.f, 0.f};

    mb = mrow[0];
    stageK(0, 0); stageV(0, 0);
    WAITBAR(0);  // drain mrow[0] + stage(0)

    float* attn_row = attn + (size_t)bh * SEQ * SEQ + (size_t)(row16 + lr) * SEQ;
    unsigned pk[4][2];
    cur = 0;
    for (int t = 0; t < NT; ++t) {
        // VMEM issue order: [leftover stores(t-1)] mrow(t+1)[1],
        // stage(t+1)[4], <compute QK>, stores(t)[4], <PV>, WAITBAR(4)
        if (t < NT - 1) {
            mn_ = mrow[t + 1];
            stageK(t + 1, cur ^ 1);
            stageV(t + 1, cur ^ 1);
        }
#pragma unroll
        for (int c = 0; c < 4; ++c) {
            const int cb = (c >> 1) * 32 + (c & 1) * 4;
            const int krow = cb + kperm;
            short8 kf0 = lds_frag(kstage[cur], krow, lgi);
            short8 kf1 = lds_frag(kstage[cur], krow, 4 + lgi);
            f32x4 acc = {0.f, 0.f, 0.f, 0.f};
            acc = __builtin_amdgcn_mfma_f32_16x16x32_bf16(kf0, qf0, acc, 0, 0, 0);
            acc = __builtin_amdgcn_mfma_f32_16x16x32_bf16(kf1, qf1, acc, 0, 0, 0);
            const unsigned b4 = (unsigned)(mb >> (cb + lgi * 8)) & 0xFu;
            float p0 = (b4 & 1u) ? __expf(acc[0] * 0.125f) * linv : 0.f;
            float p1 = (b4 & 2u) ? __expf(acc[1] * 0.125f) * linv : 0.f;
            float p2 = (b4 & 4u) ? __expf(acc[2] * 0.125f) * linv : 0.f;
            float p3 = (b4 & 8u) ? __expf(acc[3] * 0.125f) * linv : 0.f;
            pk[c][0] = pack2bf(p0, p1);
            pk[c][1] = pack2bf(p2, p3);
        }
        // attn stores for tile t (fresh pk; issued before PV so they're the
        // newest VMEM ops at the barrier and stay in flight)
#pragma unroll
        for (int c = 0; c < 4; ++c) {
            const int cb = (c >> 1) * 32 + (c & 1) * 4;
            const unsigned u01 = pk[c][0];
            const unsigned u23 = pk[c][1];
            float f0 = __uint_as_float(u01 << 16);
            float f1 = __uint_as_float(u01 & 0xffff0000u);
            float f2 = __uint_as_float(u23 << 16);
            float f3 = __uint_as_float(u23 & 0xffff0000u);
            *reinterpret_cast<float4*>(attn_row + t * 64 + cb + lgi * 8) =
                (float4){f0, f1, f2, f3};
        }
        // PV on normalized p (register-concat fragments, validated mapping)
        union { unsigned u[4]; short8 s; } pf0, pf1;
        pf0.u[0] = pk[0][0]; pf0.u[1] = pk[0][1];
        pf0.u[2] = pk[1][0]; pf0.u[3] = pk[1][1];
        pf1.u[0] = pk[2][0]; pf1.u[1] = pk[2][1];
        pf1.u[2] = pk[3][0]; pf1.u[3] = pk[3][1];
#pragma unroll
        for (int c2 = 0; c2 < 4; ++c2) {
            const int vrow = c2 * 16 + lr;
            short8 vf0 = lds_frag(vstage[cur], vrow, lgi);
            short8 vf1 = lds_frag(vstage[cur], vrow, 4 + lgi);
            o[c2] = __builtin_amdgcn_mfma_f32_16x16x32_bf16(pf0.s, vf0, o[c2], 0, 0, 0);
            o[c2] = __builtin_amdgcn_mfma_f32_16x16x32_bf16(pf1.s, vf1, o[c2], 0, 0, 0);
        }
        if (t < NT - 1) {
            mb = mn_;
            // ledger (oldest->newest): [stores(t-1) leftovers], mrow(t+1)[1],
            // stage(t+1)[4], stores(t)[4] -> drain stage(t+1), leave stores(t).
            WAITBAR(4);
        }
        cur ^= 1;
    }

    // ---- O epilogue: already normalized ----
    float* ob = out + (size_t)bh * SEQ * DIM + (size_t)row16 * DIM;
#pragma unroll
    for (int c2 = 0; c2 < 4; ++c2)
#pragma unroll
        for (int j = 0; j < 4; ++j)
            ob[(size_t)(lgi * 4 + j) * DIM + c2 * 16 + lr] = o[c2][j];
}

extern "C" void kernel_launch(void* const* d_in, const int* in_sizes, int n_in,
                              void* d_out, int out_size, void* d_ws, size_t ws_size,
                              hipStream_t stream) {
    const float* q   = (const float*)d_in[0];
    const float* k   = (const float*)d_in[1];
    const float* v   = (const float*)d_in[2];
    const int*   adj = (const int*)d_in[3];

    float* out  = (float*)d_out;                   // [32,1024,64]
    float* attn = out + (size_t)A_TOT * SEQ * DIM; // [32,1024,1024]

    __hip_bfloat16* qb = (__hip_bfloat16*)d_ws;
    __hip_bfloat16* kb = qb + (size_t)A_TOT * SEQ * DIM;
    __hip_bfloat16* vt = kb + (size_t)A_TOT * SEQ * DIM;
    u64* adjm = (u64*)(vt + (size_t)A_TOT * SEQ * DIM);  // 512 KB

    prepass_kernel<<<dim3(2048, 3), 256, 0, stream>>>(q, k, v, adj, qb, kb, vt, adjm);
    graph_attn_kernel<<<512, 256, 0, stream>>>(qb, kb, vt, adjm, out, attn);
}